// Round 12
// baseline (21.482 us; speedup 1.0000x reference)
//
#include <hip/hip_runtime.h>
#include <math.h>

// Problem constants
#define C_CH   256
#define H_DIM  26
#define W_DIM  26
#define HW     (H_DIM * W_DIM)      // 676
#define N_BOX  128
#define OUTP   3
#define NBIN   (OUTP * OUTP)        // 9
#define FEAT   (C_CH * NBIN)        // 2304
#define H1     1024
#define H2     512

// L1 grid layout: [0,64) v-blocks, [64,1216) ROI, [1216,1792) gemv
#define V_BLOCKS   64                   // 16 v-rows each
#define ROI_BLOCKS (N_BOX * NBIN)       // 1152
#define G_BLOCKS   (FEAT / 4)           // 576, 4 W1-rows each
#define ROI0       V_BLOCKS
#define G0         (V_BLOCKS + ROI_BLOCKS)      // 1216
#define L1_BLOCKS  (G0 + G_BLOCKS)              // 1792

#define TOKEN      0x5EED5EEDu
#define SPIN_MAX   50000

#define NEGINF (-INFINITY)
#define AL(p)    __hip_atomic_load((p),        __ATOMIC_RELAXED, __HIP_MEMORY_SCOPE_AGENT)
#define AS(p, x) __hip_atomic_store((p), (x), __ATOMIC_RELAXED, __HIP_MEMORY_SCOPE_AGENT)

// ---------------------------------------------------------------------------
// Wave-per-row GEMV, compile-time K -> fully unrolled f4 loads (ILP).
// Lane 0 holds the wave-reduced dot(M[r,:], v). v may be LDS or global.
// ---------------------------------------------------------------------------
template <int K>
__device__ __forceinline__ float gemv_row(const float* __restrict__ M,
                                          const float* v, int r, int lane) {
    const float4* row = (const float4*)(M + (size_t)r * K);
    const float4* vq  = (const float4*)v;
    float s = 0.f;
    #pragma unroll
    for (int i = 0; i < K / 256; i++) {
        int k4 = i * 64 + lane;
        float4 a = row[k4], b = vq[k4];
        s += a.x * b.x + a.y * b.y + a.z * b.z + a.w * b.w;
    }
    #pragma unroll
    for (int off = 32; off; off >>= 1) s += __shfl_down(s, off, 64);
    return s;
}

// ---------------------------------------------------------------------------
// L1:
//  blocks 0..63    : 16 rows of v = W2@w3 each; AS v values, barrier-drain,
//                    AS vflag[b]=TOKEN. (Only intra-launch dependency edge.)
//  blocks 64..1215 : ROI adaptive-max direct from x, one block per (box,bin);
//                    lane = c_sub*8 + w_sub packing. Plain stores to
//                    feats[n][bin*256+c] (coherent for L2 via launch boundary).
//  blocks 1216..1791: poll 64 vflags (one count-round, s_sleep backoff),
//                    AL-stage v to LDS, GEMV 4 W1-rows, plain-store
//                    wvec[bin*256+c]. Stale-TOKEN replay reads are benign:
//                    v is value-identical every call.
// ---------------------------------------------------------------------------
__global__ __launch_bounds__(256, 4)
void k1(const float* __restrict__ W2, const float* __restrict__ w3,
        const float* __restrict__ W1,
        const float* __restrict__ x, const int* __restrict__ det,
        float* v, unsigned* vflag,
        float* __restrict__ feats, float* __restrict__ wvec) {
    __shared__ __align__(16) float sv[H1];
    int b = blockIdx.x, tid = threadIdx.x;
    int lane = tid & 63, wid = tid >> 6;

    if (b < V_BLOCKS) {
        // ---- v rows b*16 .. b*16+15 (4 per wave) ----
        #pragma unroll
        for (int i = 0; i < 4; i++) {
            int r = b * 16 + wid * 4 + i;
            float s = gemv_row<H2>(W2, w3, r, lane);
            if (lane == 0) AS(&v[r], s);
        }
        __syncthreads();                     // vmcnt(0) drain: v stores done
        if (tid == 0) AS(&vflag[b], TOKEN);
        return;
    }

    if (b >= G0) {
        // ---- W1 GEMV rows 4g..4g+3 ----
        int g = b - G0;
        for (int it = 0;; ++it) {            // poll the 64 v flags
            int bad = (tid < V_BLOCKS && AL(&vflag[tid]) != TOKEN) ? 1 : 0;
            if (__syncthreads_count(bad) == 0) break;
            if (it > SPIN_MAX) break;        // fail loudly via absmax, no hang
            __builtin_amdgcn_s_sleep(4);
        }
        #pragma unroll
        for (int i = 0; i < H1 / 256; i++) sv[i * 256 + tid] = AL(&v[i * 256 + tid]);
        __syncthreads();

        int r = g * 4 + wid;                 // r = c*9 + bin
        float s = gemv_row<H1>(W1, sv, r, lane);
        if (lane == 0) wvec[(r % NBIN) * C_CH + (r / NBIN)] = s;
        return;
    }

    // ---------------- ROI pooling (direct x reads) ----------------
    int nbx = b - ROI0;
    int n = nbx / NBIN, bin = nbx - n * NBIN;
    int bi = bin / OUTP, bj = bin - bi * OUTP;

    int x1 = det[n * 4 + 0], y1 = det[n * 4 + 1];
    int x2 = det[n * 4 + 2], y2 = det[n * 4 + 3];
    int hl = y2 - y1 + 1, wl = x2 - x1 + 1;

    int h0  = y1 + (bi * hl) / OUTP;
    int h1e = y1 + ((bi + 1) * hl + OUTP - 1) / OUTP;   // ceil
    int w0  = x1 + (bj * wl) / OUTP;
    int w1e = x1 + ((bj + 1) * wl + OUTP - 1) / OUTP;
    int hb = h1e - h0, wb = w1e - w0;                    // 1..10 each

    int c_sub = lane >> 3;       // 0..7
    int w_sub = lane & 7;        // 0..7
    int c0    = wid * 64;

    bool p1 = (w_sub < wb);
    bool p2 = (w_sub + 8 < wb);  // wb up to 10

    float m[8];
    #pragma unroll
    for (int i = 0; i < 8; i++) m[i] = NEGINF;

    for (int h = 0; h < hb; h++) {
        const float* ph = x + (size_t)(h0 + h) * W_DIM + (w0 + w_sub);
        #pragma unroll
        for (int ci = 0; ci < 8; ci++) {     // 8 independent load chains
            const float* pc = ph + (size_t)(c0 + ci * 8 + c_sub) * HW;
            float v1 = p1 ? pc[0] : NEGINF;
            float v2 = p2 ? pc[8] : NEGINF;
            m[ci] = fmaxf(m[ci], fmaxf(v1, v2));
        }
    }
    #pragma unroll
    for (int mask = 1; mask < 8; mask <<= 1) {
        #pragma unroll
        for (int ci = 0; ci < 8; ci++)
            m[ci] = fmaxf(m[ci], __shfl_xor(m[ci], mask, 64));
    }
    if (w_sub == 0) {
        #pragma unroll
        for (int ci = 0; ci < 8; ci++) {
            int c = c0 + ci * 8 + c_sub;
            feats[(size_t)n * FEAT + bin * C_CH + c] = m[ci];
        }
    }
}

// ---------------------------------------------------------------------------
// L2: one block per box. Redundant collapsed bias (b1.v + b2.w3 + b3, plain
// loads -- launch boundary makes L1's v coherent), coalesced 9-per-thread
// dot, block reduce, softplus. Fixed order -> deterministic.
// ---------------------------------------------------------------------------
__global__ __launch_bounds__(256, 4)
void k2(const float* __restrict__ feats, const float* __restrict__ wvec,
        const float* __restrict__ v,
        const float* __restrict__ b1, const float* __restrict__ b2,
        const float* __restrict__ w3, const float* __restrict__ b3,
        float* __restrict__ out) {
    __shared__ float red[4];
    __shared__ float cbs;
    int n = blockIdx.x, tid = threadIdx.x;
    int lane = tid & 63, wid = tid >> 6;

    // collapsed bias
    float sb = 0.f;
    for (int k = tid; k < H1; k += 256) sb += b1[k] * v[k];
    for (int k = tid; k < H2; k += 256) sb += b2[k] * w3[k];
    #pragma unroll
    for (int off = 32; off; off >>= 1) sb += __shfl_down(sb, off, 64);
    if (lane == 0) red[wid] = sb;
    __syncthreads();
    if (tid == 0) cbs = red[0] + red[1] + red[2] + red[3] + b3[0];
    __syncthreads();

    // dot(feats[n], wvec)
    const float* fn = feats + (size_t)n * FEAT;
    float s = 0.f;
    #pragma unroll
    for (int i = 0; i < NBIN; i++) {
        int f = i * 256 + tid;
        s += fn[f] * wvec[f];
    }
    #pragma unroll
    for (int off = 32; off; off >>= 1) s += __shfl_down(s, off, 64);
    if (lane == 0) red[wid] = s;
    __syncthreads();
    if (tid == 0) {
        float r = red[0] + red[1] + red[2] + red[3] + cbs;
        out[n] = fmaxf(r, 0.f) + log1pf(expf(-fabsf(r)));   // stable softplus
    }
}

extern "C" void kernel_launch(void* const* d_in, const int* in_sizes, int n_in,
                              void* d_out, int out_size, void* d_ws, size_t ws_size,
                              hipStream_t stream) {
    const float* x   = (const float*)d_in[0];
    const int*   det = (const int*)  d_in[1];
    const float* W1  = (const float*)d_in[2];
    const float* b1  = (const float*)d_in[3];
    const float* W2  = (const float*)d_in[4];
    const float* b2  = (const float*)d_in[5];
    const float* W3  = (const float*)d_in[6];
    const float* b3  = (const float*)d_in[7];
    float* out = (float*)d_out;

    // workspace layout (floats / u32)
    float* ws    = (float*)d_ws;
    float* v     = ws;                               // 1024
    float* wvec  = v + H1;                           // 2304 (bin-major)
    float* feats = wvec + FEAT;                      // 128*2304 = 294912
    unsigned* vflag = (unsigned*)(feats + (size_t)N_BOX * FEAT);  // 64

    k1<<<L1_BLOCKS, 256, 0, stream>>>(W2, W3, W1, x, det, v, vflag, feats, wvec);
    k2<<<N_BOX, 256, 0, stream>>>(feats, wvec, v, b1, b2, W3, b3, out);
}

// Round 13
// 21.145 us; speedup vs baseline: 1.0159x; 1.0159x over previous
//
#include <hip/hip_runtime.h>
#include <math.h>

// Problem constants
#define C_CH   256
#define H_DIM  26
#define W_DIM  26
#define HW     (H_DIM * W_DIM)      // 676
#define N_BOX  128
#define OUTP   3
#define NBIN   (OUTP * OUTP)        // 9
#define FEAT   (C_CH * NBIN)        // 2304
#define H1     1024
#define H2     512

// k-sliced chain: p[f][j] = sum_{k in slice j} W1[f,k] * v[k],  v = W2@w3
#define NJ     16                   // k-slices of width 64
#define SLICE  64                   // H1 / NJ
#define RC     9                    // row-chunks of 256 rows (1 row/thread)
#define CHAIN_BLOCKS (NJ * RC)      // 144
#define ROI_BLOCKS   (N_BOX * NBIN) // 1152
#define L1_BLOCKS    (CHAIN_BLOCKS + ROI_BLOCKS)   // 1296
#define PB     (FEAT * NJ)          // bias-partial base offset in p (36864)

#define NEGINF (-INFINITY)

// ---------------------------------------------------------------------------
// Wave-per-row GEMV, compile-time K -> fully unrolled f4 loads.
// Lane 0 holds the wave-reduced dot(M[r,:], v).
// ---------------------------------------------------------------------------
template <int K>
__device__ __forceinline__ float gemv_row(const float* __restrict__ M,
                                          const float* __restrict__ v,
                                          int r, int lane) {
    const float4* row = (const float4*)(M + (size_t)r * K);
    const float4* vq  = (const float4*)v;
    float s = 0.f;
    #pragma unroll
    for (int i = 0; i < K / 256; i++) {
        int k4 = i * 64 + lane;
        float4 a = row[k4], b = vq[k4];
        s += a.x * b.x + a.y * b.y + a.z * b.z + a.w * b.w;
    }
    #pragma unroll
    for (int off = 32; off; off >>= 1) s += __shfl_down(s, off, 64);
    return s;
}

// ---------------------------------------------------------------------------
// K1 (single launch, zero intra-launch dependencies):
//  blocks 0..143: chain block (j,rc), XCD-colocated per slice (b%8 == j%8 so
//    all 9 rc-copies of slice j share an XCD L2 -> W2 slice fetched ~once).
//    - issue 16 W1 f4 loads EARLY (rows rc*256+tid, cols j*64..j*64+63)
//    - stage 1: v_lds[0..63] = W2[j*64+i,:] . w3   (16 rows/wave, unrolled)
//    - stage 2: p[f][j] = dot64(W1 row, v_lds)   (1 row/thread, f=bin*256+c)
//    - rc==0: p[PB+j] = b1[slice j] . v_lds      (bias partial)
//  blocks 144..1295: ROI adaptive-max direct from x (proven path), writes
//    feats[n][bin*256+c]. Plain stores; launch boundary publishes all.
// ---------------------------------------------------------------------------
__global__ __launch_bounds__(256)
void k1(const float* __restrict__ W2, const float* __restrict__ w3,
        const float* __restrict__ W1, const float* __restrict__ b1,
        const float* __restrict__ x, const int* __restrict__ det,
        float* __restrict__ p, float* __restrict__ feats) {
    int b = blockIdx.x, tid = threadIdx.x;
    int lane = tid & 63, wid = tid >> 6;

    if (b < CHAIN_BLOCKS) {
        __shared__ __align__(16) float v_lds[SLICE];
        // decode with XCD co-location: b = (j%8) + 8*(rc*2 + j/8)
        int t  = b >> 3;
        int j  = (b & 7) + 8 * (t & 1);      // 0..15
        int rc = t >> 1;                     // 0..8
        int r  = rc * 256 + tid;             // W1 row (feature r = c*9+bin)

        // ---- early W1 loads: 16 independent f4, latency hidden by stage 1
        const float4* wrow = (const float4*)(W1 + (size_t)r * H1 + j * SLICE);
        float4 a[16];
        #pragma unroll
        for (int q = 0; q < 16; q++) a[q] = wrow[q];

        // ---- stage 1: v-slice (64 rows of W2, 16 per wave, unrolled)
        #pragma unroll
        for (int ii = 0; ii < 16; ii++) {
            int i = wid * 16 + ii;
            float s = gemv_row<H2>(W2, w3, j * SLICE + i, lane);
            if (lane == 0) v_lds[i] = s;
        }
        __syncthreads();

        // ---- stage 2: one 64-wide dot per thread (LDS reads broadcast)
        const float4* vq = (const float4*)v_lds;
        float acc = 0.f;
        #pragma unroll
        for (int q = 0; q < 16; q++) {
            float4 vv = vq[q];
            acc += a[q].x * vv.x + a[q].y * vv.y + a[q].z * vv.z + a[q].w * vv.w;
        }
        int c = r / NBIN, bin = r - c * NBIN;
        p[(size_t)(bin * C_CH + c) * NJ + j] = acc;     // [f][j] layout

        // ---- bias partial: p[PB+j] = b1[slice j].v_lds (wave 0 of rc==0)
        if (rc == 0 && wid == 0) {
            float bb = b1[j * SLICE + lane] * v_lds[lane];
            #pragma unroll
            for (int off = 32; off; off >>= 1) bb += __shfl_down(bb, off, 64);
            if (lane == 0) p[PB + j] = bb;
        }
        return;
    }

    // ---------------- ROI pooling (direct x reads, proven) ----------------
    int nbx = b - CHAIN_BLOCKS;
    int n = nbx / NBIN, bin = nbx - n * NBIN;
    int bi = bin / OUTP, bj = bin - bi * OUTP;

    int x1 = det[n * 4 + 0], y1 = det[n * 4 + 1];
    int x2 = det[n * 4 + 2], y2 = det[n * 4 + 3];
    int hl = y2 - y1 + 1, wl = x2 - x1 + 1;

    int h0  = y1 + (bi * hl) / OUTP;
    int h1e = y1 + ((bi + 1) * hl + OUTP - 1) / OUTP;   // ceil
    int w0  = x1 + (bj * wl) / OUTP;
    int w1e = x1 + ((bj + 1) * wl + OUTP - 1) / OUTP;
    int hb = h1e - h0, wb = w1e - w0;                    // 1..10 each

    int c_sub = lane >> 3;       // 0..7
    int w_sub = lane & 7;        // 0..7
    int c0    = wid * 64;

    bool g1 = (w_sub < wb);
    bool g2 = (w_sub + 8 < wb);  // wb up to 10

    float m[8];
    #pragma unroll
    for (int i = 0; i < 8; i++) m[i] = NEGINF;

    for (int h = 0; h < hb; h++) {
        const float* ph = x + (size_t)(h0 + h) * W_DIM + (w0 + w_sub);
        #pragma unroll
        for (int ci = 0; ci < 8; ci++) {     // 8 independent load chains
            const float* pc = ph + (size_t)(c0 + ci * 8 + c_sub) * HW;
            float v1 = g1 ? pc[0] : NEGINF;
            float v2 = g2 ? pc[8] : NEGINF;
            m[ci] = fmaxf(m[ci], fmaxf(v1, v2));
        }
    }
    #pragma unroll
    for (int mask = 1; mask < 8; mask <<= 1) {
        #pragma unroll
        for (int ci = 0; ci < 8; ci++)
            m[ci] = fmaxf(m[ci], __shfl_xor(m[ci], mask, 64));
    }
    if (w_sub == 0) {
        #pragma unroll
        for (int ci = 0; ci < 8; ci++) {
            int c = c0 + ci * 8 + c_sub;
            feats[(size_t)n * FEAT + bin * C_CH + c] = m[ci];
        }
    }
}

// ---------------------------------------------------------------------------
// KF: one block per box.
//   s = sum_f feats[n][f] * (sum_j p[f][j])      (4 dense f4 loads per f)
//     + sum_j p[PB+j]  (b1.v)  + b2.w3 + b3   -> softplus -> out[n].
// Fixed summation order everywhere -> deterministic.
// ---------------------------------------------------------------------------
__global__ __launch_bounds__(256)
void kF(const float* __restrict__ p, const float* __restrict__ feats,
        const float* __restrict__ b2, const float* __restrict__ w3,
        const float* __restrict__ b3, float* __restrict__ out) {
    __shared__ float red[4];
    int n = blockIdx.x, tid = threadIdx.x;
    int lane = tid & 63, wid = tid >> 6;

    const float*  fn = feats + (size_t)n * FEAT;
    const float4* p4 = (const float4*)p;

    float s = 0.f;
    #pragma unroll
    for (int i = 0; i < NBIN; i++) {         // 9 features/thread, 36 f4 in flight
        int f = i * 256 + tid;
        float4 q0 = p4[f * 4 + 0], q1 = p4[f * 4 + 1];
        float4 q2 = p4[f * 4 + 2], q3 = p4[f * 4 + 3];
        float ws = (((q0.x + q0.y) + (q0.z + q0.w)) + ((q1.x + q1.y) + (q1.z + q1.w)))
                 + (((q2.x + q2.y) + (q2.z + q2.w)) + ((q3.x + q3.y) + (q3.z + q3.w)));
        s += fn[f] * ws;
    }
    if (tid < NJ) s += p[PB + tid];          // b1.v partials
    for (int k = tid; k < H2; k += 256) s += b2[k] * w3[k];

    #pragma unroll
    for (int off = 32; off; off >>= 1) s += __shfl_down(s, off, 64);
    if (lane == 0) red[wid] = s;
    __syncthreads();
    if (tid == 0) {
        float r = red[0] + red[1] + red[2] + red[3] + b3[0];
        out[n] = fmaxf(r, 0.f) + log1pf(expf(-fabsf(r)));   // stable softplus
    }
}

extern "C" void kernel_launch(void* const* d_in, const int* in_sizes, int n_in,
                              void* d_out, int out_size, void* d_ws, size_t ws_size,
                              hipStream_t stream) {
    const float* x   = (const float*)d_in[0];
    const int*   det = (const int*)  d_in[1];
    const float* W1  = (const float*)d_in[2];
    const float* b1  = (const float*)d_in[3];
    const float* W2  = (const float*)d_in[4];
    const float* b2  = (const float*)d_in[5];
    const float* W3  = (const float*)d_in[6];
    const float* b3  = (const float*)d_in[7];
    float* out = (float*)d_out;

    // workspace layout (floats)
    float* ws    = (float*)d_ws;
    float* p     = ws;                        // FEAT*NJ + NJ = 36880
    float* feats = p + (PB + NJ);             // 128*2304 = 294912

    k1<<<L1_BLOCKS, 256, 0, stream>>>(W2, W3, W1, b1, x, det, p, feats);
    kF<<<N_BOX, 256, 0, stream>>>(p, feats, b2, W3, b3, out);
}